// Round 4
// baseline (1093.629 us; speedup 1.0000x reference)
//
#include <hip/hip_runtime.h>
#include <hip/hip_bf16.h>

// LSAPPNP: h = relu(x@W1+b1); h2 = h@W2+b2; agg[r] += val*h2[c] over edges;
// out = log_softmax(0.1*h2 + agg, axis=1)
// N=100000, F_IN=500, HID=256, C=40, E~2.3M
//
// Round 4: replace per-edge device atomics + random 8B scatter (146 MB line
// churn) with coarse 128-row buckets: LDS histogram -> scan -> locality-
// friendly split -> per-bucket LDS-accumulator SpMM with fused log_softmax.

#define N_NODES 100000
#define F_IN    500
#define HID     256
#define C_OUT   40
#define ALPHA0  0.1f

#define RPB     128                       // rows per bucket
#define NBUCK   ((N_NODES + RPB - 1) / RPB)   // 782
#define NCH     640                       // edge chunks (hist/split blocks)
#define SCAN_M  (NBUCK * NCH)             // 500480 scan elements
#define SCAN_CHUNK 2048
#define NBS     ((SCAN_M + SCAN_CHUNK - 1) / SCAN_CHUNK)  // 245

typedef short short8 __attribute__((ext_vector_type(8)));
typedef float f32x4  __attribute__((ext_vector_type(4)));

__device__ __forceinline__ short f2bf(float f) {
  union { float f; unsigned u; } x; x.f = f;
  unsigned r = x.u + 0x7fffu + ((x.u >> 16) & 1u);  // RNE
  return (short)(r >> 16);
}
__device__ __forceinline__ float bf2f(short s) {
  union { unsigned u; float f; } x; x.u = ((unsigned)(unsigned short)s) << 16;
  return x.f;
}

// ---- K0: pack W1 -> W1S [16 kchunks][256 n][32 k] bf16; W2 -> W2T [48 n][256 k]
__global__ __launch_bounds__(256) void k_pack_weights(
    const float* __restrict__ W1, const float* __restrict__ W2,
    short* __restrict__ W1S, short* __restrict__ W2T)
{
  int i = blockIdx.x * 256 + threadIdx.x;
  if (i < 16*256*32) {
    int kc  = i >> 13;
    int idx = i & 8191;
    int n   = idx >> 5;
    int kk  = idx & 31;
    int k   = kc*32 + kk;
    float v = (k < F_IN) ? W1[k*HID + n] : 0.f;
    W1S[i] = f2bf(v);
  } else {
    int j = i - 16*256*32;
    if (j < 48*256) {
      int n = j >> 8;
      int k = j & 255;
      float v = (n < C_OUT) ? W2[k*C_OUT + n] : 0.f;
      W2T[j] = f2bf(v);
    }
  }
}

// ---- K1: fused MLP. Block = 256 thr (4 waves), tile = 64 rows x 256.
__global__ __launch_bounds__(256) void k_fused_mlp(
    const float* __restrict__ x, const float* __restrict__ b1v,
    const float* __restrict__ b2v,
    const short* __restrict__ W1S, const short* __restrict__ W2T,
    short* __restrict__ h2b)
{
  __shared__ __align__(16) char smem[57344];
  short (*Al)[32]   = (short(*)[32])smem;
  short (*Bl)[32]   = (short(*)[32])(smem + 4096);
  short (*Hl)[256]  = (short(*)[256])smem;            // overlaps Al+Bl
  short (*W2l)[256] = (short(*)[256])(smem + 32768);

  const int tid  = threadIdx.x;
  const int wave = tid >> 6;
  const int lane = tid & 63;
  const int lr   = lane & 15;
  const int quad = lane >> 4;
  const int row0 = blockIdx.x * 64;

  {
    const short8* src = (const short8*)W2T;
    short8* dst = (short8*)&W2l[0][0];
    #pragma unroll
    for (int it = 0; it < 6; ++it)
      dst[it*256 + tid] = src[it*256 + tid];
  }

  f32x4 acc[4][4] = {};

  const int ar = tid >> 2;
  const int aq = tid & 3;
  const bool arow_ok = (row0 + ar) < N_NODES;
  const float* asrc = x + (long)(row0 + ar) * F_IN + aq*8;

  for (int kc = 0; kc < 16; ++kc) {
    {
      short tmp[8];
      int kbase = kc*32 + aq*8;
      if (arow_ok) {
        #pragma unroll
        for (int j = 0; j < 8; ++j) {
          float v = (kbase + j < F_IN) ? asrc[kc*32 + j] : 0.f;
          tmp[j] = f2bf(v);
        }
      } else {
        #pragma unroll
        for (int j = 0; j < 8; ++j) tmp[j] = 0;
      }
      *(short8*)&Al[ar][aq*8] = *(short8*)tmp;
    }
    {
      const short* src = W1S + kc*8192 + tid*32;
      short* dst = &Bl[0][0] + tid*32;
      #pragma unroll
      for (int j = 0; j < 4; ++j)
        *(short8*)(dst + j*8) = *(const short8*)(src + j*8);
    }
    __syncthreads();

    short8 af[4], bfr[4];
    #pragma unroll
    for (int t = 0; t < 4; ++t) af[t]  = *(const short8*)&Al[t*16 + lr][quad*8];
    #pragma unroll
    for (int t = 0; t < 4; ++t) bfr[t] = *(const short8*)&Bl[wave*64 + t*16 + lr][quad*8];

    #pragma unroll
    for (int rt = 0; rt < 4; ++rt)
      #pragma unroll
      for (int ct = 0; ct < 4; ++ct)
        acc[rt][ct] = __builtin_amdgcn_mfma_f32_16x16x32_bf16(af[rt], bfr[ct], acc[rt][ct], 0, 0, 0);

    __syncthreads();
  }

  // epilogue 1: relu(acc + b1) -> Hl bf16. D layout: col=lane&15, row=quad*4+reg
  #pragma unroll
  for (int ct = 0; ct < 4; ++ct) {
    int col = wave*64 + ct*16 + lr;
    float bias = b1v[col];
    #pragma unroll
    for (int rt = 0; rt < 4; ++rt) {
      #pragma unroll
      for (int r = 0; r < 4; ++r) {
        int row = rt*16 + quad*4 + r;
        float v = fmaxf(acc[rt][ct][r] + bias, 0.f);
        Hl[row][col] = f2bf(v);
      }
    }
  }
  __syncthreads();

  // GEMM2: each wave rows wave*16..+15, 48 padded cols, K=256
  f32x4 acc2[3] = {};
  #pragma unroll
  for (int kc2 = 0; kc2 < 8; ++kc2) {
    short8 a2 = *(const short8*)&Hl[wave*16 + lr][kc2*32 + quad*8];
    #pragma unroll
    for (int nt = 0; nt < 3; ++nt) {
      short8 bq = *(const short8*)&W2l[nt*16 + lr][kc2*32 + quad*8];
      acc2[nt] = __builtin_amdgcn_mfma_f32_16x16x32_bf16(a2, bq, acc2[nt], 0, 0, 0);
    }
  }

  // epilogue 2: h2b = bf16(acc2 + b2)
  #pragma unroll
  for (int nt = 0; nt < 3; ++nt) {
    int col = nt*16 + lr;
    if (col < C_OUT) {
      float bias = b2v[col];
      #pragma unroll
      for (int r = 0; r < 4; ++r) {
        int row = row0 + wave*16 + quad*4 + r;
        if (row < N_NODES)
          h2b[(long)row * C_OUT + col] = f2bf(acc2[nt][r] + bias);
      }
    }
  }
}

// ---- K2: per-chunk LDS histogram of buckets (row>>7). offs[b*NCH + c] = count
__global__ __launch_bounds__(256) void k_hist2(
    const int* __restrict__ erow, int* __restrict__ offs, int E, int CH)
{
  __shared__ int h[NBUCK];
  int tid = threadIdx.x, c = blockIdx.x;
  for (int b = tid; b < NBUCK; b += 256) h[b] = 0;
  __syncthreads();
  int e0 = c * CH, e1 = min(E, e0 + CH);
  for (int e = e0 + tid; e < e1; e += 256)
    atomicAdd(&h[erow[e] >> 7], 1);
  __syncthreads();
  for (int b = tid; b < NBUCK; b += 256) offs[b * NCH + c] = h[b];
}

// ---- K3a: scan phase 1 — 2048-elem chunks, in-place exclusive scan + sums
__global__ __launch_bounds__(256) void k_scan1(
    int* __restrict__ offs, int* __restrict__ bsums)
{
  __shared__ int sh[256];
  int tid = threadIdx.x;
  int base = blockIdx.x * SCAN_CHUNK + tid * 8;
  int d[8];
  #pragma unroll
  for (int k = 0; k < 8; ++k)
    d[k] = (base + k < SCAN_M) ? offs[base + k] : 0;
  int s = 0;
  #pragma unroll
  for (int k = 0; k < 8; ++k) s += d[k];
  sh[tid] = s;
  __syncthreads();
  for (int o = 1; o < 256; o <<= 1) {
    int v = (tid >= o) ? sh[tid - o] : 0;
    __syncthreads();
    if (tid >= o) sh[tid] += v;
    __syncthreads();
  }
  int run = sh[tid] - s;
  #pragma unroll
  for (int k = 0; k < 8; ++k) {
    if (base + k < SCAN_M) offs[base + k] = run;
    run += d[k];
  }
  if (tid == 255) bsums[blockIdx.x] = sh[255];
}

// ---- K3b: scan phase 2 — exclusive scan of NBS block sums (single block)
__global__ __launch_bounds__(256) void k_scan2(int* __restrict__ bsums) {
  __shared__ int sh[256];
  int tid = threadIdx.x;
  int v = (tid < NBS) ? bsums[tid] : 0;
  sh[tid] = v;
  __syncthreads();
  for (int o = 1; o < 256; o <<= 1) {
    int u = (tid >= o) ? sh[tid - o] : 0;
    __syncthreads();
    if (tid >= o) sh[tid] += u;
    __syncthreads();
  }
  if (tid < NBS) bsums[tid] = sh[tid] - v;
}

// ---- K3c: scan phase 3 — add block offsets
__global__ __launch_bounds__(256) void k_scan3(
    int* __restrict__ offs, const int* __restrict__ bsums)
{
  int i = blockIdx.x * 256 + threadIdx.x;
  if (i < SCAN_M) offs[i] += bsums[i >> 11];
}

// ---- K4: split edges into bucket-grouped order.
// sorted[pos] = { col | rowlow<<17 , val }. LDS cursors: no device atomics;
// each (block,bucket) run is contiguous + temporally clustered -> L2 merges.
__global__ __launch_bounds__(256) void k_split(
    const int* __restrict__ erow, const int* __restrict__ ecol,
    const float* __restrict__ eval, const int* __restrict__ offs,
    int2* __restrict__ sorted, int E, int CH)
{
  __shared__ int cur[NBUCK];
  int tid = threadIdx.x, c = blockIdx.x;
  for (int b = tid; b < NBUCK; b += 256) cur[b] = offs[b * NCH + c];
  __syncthreads();
  int e0 = c * CH, e1 = min(E, e0 + CH);
  for (int e = e0 + tid; e < e1; e += 256) {
    int r = erow[e];
    int b = r >> 7;
    int pos = atomicAdd(&cur[b], 1);
    int2 cv;
    cv.x = ecol[e] | ((r & 127) << 17);
    cv.y = __float_as_int(eval[e]);
    sorted[pos] = cv;
  }
}

// ---- K5: per-bucket SpMM (LDS f32 accumulators) + fused log_softmax.
__global__ __launch_bounds__(256) void k_spmm_lsm(
    const int* __restrict__ offs, const int2* __restrict__ sorted,
    const short* __restrict__ h2b, float* __restrict__ out, int E)
{
  __shared__ float acc[RPB][C_OUT];    // 20 KB
  int tid = threadIdx.x, b = blockIdx.x;
  int wave = tid >> 6, lane = tid & 63;

  {
    float* a = &acc[0][0];
    #pragma unroll
    for (int i = tid; i < RPB * C_OUT; i += 256) a[i] = 0.f;
  }
  __syncthreads();

  int start = offs[b * NCH];
  int end   = (b + 1 < NBUCK) ? offs[(b + 1) * NCH] : E;

  int e = start + wave;
  for (; e + 4 < end; e += 8) {
    int2 cv0 = sorted[e];
    int2 cv1 = sorted[e + 4];
    int   c0 = cv0.x & 0x1FFFF, r0 = cv0.x >> 17;
    int   c1 = cv1.x & 0x1FFFF, r1 = cv1.x >> 17;
    float v0 = __int_as_float(cv0.y);
    float v1 = __int_as_float(cv1.y);
    if (lane < C_OUT) {
      float g0 = bf2f(h2b[(long)c0 * C_OUT + lane]);
      float g1 = bf2f(h2b[(long)c1 * C_OUT + lane]);
      atomicAdd(&acc[r0][lane], v0 * g0);
      atomicAdd(&acc[r1][lane], v1 * g1);
    }
  }
  for (; e < end; e += 4) {
    int2 cv = sorted[e];
    int   c0 = cv.x & 0x1FFFF, r0 = cv.x >> 17;
    float v0 = __int_as_float(cv.y);
    if (lane < C_OUT)
      atomicAdd(&acc[r0][lane], v0 * bf2f(h2b[(long)c0 * C_OUT + lane]));
  }
  __syncthreads();

  // epilogue: out = log_softmax(alpha*h2 + acc). 32 rows per wave.
  for (int rl = wave * 32; rl < wave * 32 + 32; ++rl) {
    int row = b * RPB + rl;
    if (row >= N_NODES) break;
    float v = -INFINITY;
    if (lane < C_OUT)
      v = ALPHA0 * bf2f(h2b[(long)row * C_OUT + lane]) + acc[rl][lane];
    float m = v;
    #pragma unroll
    for (int o = 32; o > 0; o >>= 1) m = fmaxf(m, __shfl_xor(m, o));
    float ev = (lane < C_OUT) ? __expf(v - m) : 0.f;
    float s = ev;
    #pragma unroll
    for (int o = 32; o > 0; o >>= 1) s += __shfl_xor(s, o);
    if (lane < C_OUT) out[(long)row * C_OUT + lane] = v - m - __logf(s);
  }
}

extern "C" void kernel_launch(void* const* d_in, const int* in_sizes, int n_in,
                              void* d_out, int out_size, void* d_ws, size_t ws_size,
                              hipStream_t stream) {
  const float* x    = (const float*)d_in[0];
  const float* W1   = (const float*)d_in[1];
  const float* b1   = (const float*)d_in[2];
  const float* W2   = (const float*)d_in[3];
  const float* b2   = (const float*)d_in[4];
  const int*   erow = (const int*)d_in[5];
  const int*   ecol = (const int*)d_in[6];
  const float* eval = (const float*)d_in[7];
  const int E  = in_sizes[5];
  const int CH = (E + NCH - 1) / NCH;

  // ws: h2b 8MB | W1S 256KB | W2T 24KB | offs 2MB | bsums 1KB | sorted E*8B (~28.7MB)
  char* p = (char*)d_ws;
  short* h2b   = (short*)p;  p += (size_t)N_NODES * C_OUT * 2;
  short* W1S   = (short*)p;  p += (size_t)16*256*32 * 2;
  short* W2T   = (short*)p;  p += (size_t)48*256 * 2;
  int*   offs  = (int*)p;    p += (size_t)SCAN_M * 4;
  int*   bsums = (int*)p;    p += 256 * 4;
  int2*  sorted = (int2*)p;
  float* out = (float*)d_out;

  k_pack_weights<<<(16*256*32 + 48*256 + 255)/256, 256, 0, stream>>>(W1, W2, W1S, W2T);
  k_fused_mlp<<<(N_NODES + 63)/64, 256, 0, stream>>>(x, b1, b2, W1S, W2T, h2b);
  k_hist2<<<NCH, 256, 0, stream>>>(erow, offs, E, CH);
  k_scan1<<<NBS, 256, 0, stream>>>(offs, bsums);
  k_scan2<<<1, 256, 0, stream>>>(bsums);
  k_scan3<<<(SCAN_M + 255)/256, 256, 0, stream>>>(offs, bsums);
  k_split<<<NCH, 256, 0, stream>>>(erow, ecol, eval, offs, sorted, E, CH);
  k_spmm_lsm<<<NBUCK, 256, 0, stream>>>(offs, sorted, h2b, out, E);
}

// Round 5
// 569.484 us; speedup vs baseline: 1.9204x; 1.9204x over previous
//
#include <hip/hip_runtime.h>
#include <hip/hip_bf16.h>

// LSAPPNP: h = relu(x@W1+b1); h2 = h@W2+b2; agg[r] += val*h2[c] over edges;
// out = log_softmax(0.1*h2 + agg, axis=1)
// N=100000, F_IN=500, HID=256, C=40, E~2.3M
//
// Round 5: bucket split (LDS cursors, low churn) -> per-bucket CSR finalize
// -> wave-per-row gather SpMM (high MLP) with fused log_softmax.

#define N_NODES 100000
#define F_IN    500
#define HID     256
#define C_OUT   40
#define ALPHA0  0.1f

#define RPB     128                           // rows per bucket
#define NBUCK   ((N_NODES + RPB - 1) / RPB)   // 782
#define NCH     320                           // edge chunks (hist/split blocks)
#define SCAN_M  (NBUCK * NCH)                 // 250240
#define SCAN_CHUNK 2048
#define NBS     ((SCAN_M + SCAN_CHUNK - 1) / SCAN_CHUNK)  // 123

typedef short short8 __attribute__((ext_vector_type(8)));
typedef float f32x4  __attribute__((ext_vector_type(4)));

__device__ __forceinline__ short f2bf(float f) {
  union { float f; unsigned u; } x; x.f = f;
  unsigned r = x.u + 0x7fffu + ((x.u >> 16) & 1u);  // RNE
  return (short)(r >> 16);
}
__device__ __forceinline__ float bf2f(short s) {
  union { unsigned u; float f; } x; x.u = ((unsigned)(unsigned short)s) << 16;
  return x.f;
}

// ---- K0: pack W1 -> W1S [16 kchunks][256 n][32 k] bf16; W2 -> W2T [48 n][256 k]
__global__ __launch_bounds__(256) void k_pack_weights(
    const float* __restrict__ W1, const float* __restrict__ W2,
    short* __restrict__ W1S, short* __restrict__ W2T)
{
  int i = blockIdx.x * 256 + threadIdx.x;
  if (i < 16*256*32) {
    int kc  = i >> 13;
    int idx = i & 8191;
    int n   = idx >> 5;
    int kk  = idx & 31;
    int k   = kc*32 + kk;
    float v = (k < F_IN) ? W1[k*HID + n] : 0.f;
    W1S[i] = f2bf(v);
  } else {
    int j = i - 16*256*32;
    if (j < 48*256) {
      int n = j >> 8;
      int k = j & 255;
      float v = (n < C_OUT) ? W2[k*C_OUT + n] : 0.f;
      W2T[j] = f2bf(v);
    }
  }
}

// ---- K1: fused MLP. Block = 256 thr (4 waves), tile = 64 rows x 256.
__global__ __launch_bounds__(256) void k_fused_mlp(
    const float* __restrict__ x, const float* __restrict__ b1v,
    const float* __restrict__ b2v,
    const short* __restrict__ W1S, const short* __restrict__ W2T,
    short* __restrict__ h2b)
{
  __shared__ __align__(16) char smem[57344];
  short (*Al)[32]   = (short(*)[32])smem;
  short (*Bl)[32]   = (short(*)[32])(smem + 4096);
  short (*Hl)[256]  = (short(*)[256])smem;            // overlaps Al+Bl
  short (*W2l)[256] = (short(*)[256])(smem + 32768);

  const int tid  = threadIdx.x;
  const int wave = tid >> 6;
  const int lane = tid & 63;
  const int lr   = lane & 15;
  const int quad = lane >> 4;
  const int row0 = blockIdx.x * 64;

  {
    const short8* src = (const short8*)W2T;
    short8* dst = (short8*)&W2l[0][0];
    #pragma unroll
    for (int it = 0; it < 6; ++it)
      dst[it*256 + tid] = src[it*256 + tid];
  }

  f32x4 acc[4][4] = {};

  const int ar = tid >> 2;
  const int aq = tid & 3;
  const bool arow_ok = (row0 + ar) < N_NODES;
  const float* asrc = x + (long)(row0 + ar) * F_IN + aq*8;

  for (int kc = 0; kc < 16; ++kc) {
    {
      short tmp[8];
      int kbase = kc*32 + aq*8;
      if (arow_ok) {
        #pragma unroll
        for (int j = 0; j < 8; ++j) {
          float v = (kbase + j < F_IN) ? asrc[kc*32 + j] : 0.f;
          tmp[j] = f2bf(v);
        }
      } else {
        #pragma unroll
        for (int j = 0; j < 8; ++j) tmp[j] = 0;
      }
      *(short8*)&Al[ar][aq*8] = *(short8*)tmp;
    }
    {
      const short* src = W1S + kc*8192 + tid*32;
      short* dst = &Bl[0][0] + tid*32;
      #pragma unroll
      for (int j = 0; j < 4; ++j)
        *(short8*)(dst + j*8) = *(const short8*)(src + j*8);
    }
    __syncthreads();

    short8 af[4], bfr[4];
    #pragma unroll
    for (int t = 0; t < 4; ++t) af[t]  = *(const short8*)&Al[t*16 + lr][quad*8];
    #pragma unroll
    for (int t = 0; t < 4; ++t) bfr[t] = *(const short8*)&Bl[wave*64 + t*16 + lr][quad*8];

    #pragma unroll
    for (int rt = 0; rt < 4; ++rt)
      #pragma unroll
      for (int ct = 0; ct < 4; ++ct)
        acc[rt][ct] = __builtin_amdgcn_mfma_f32_16x16x32_bf16(af[rt], bfr[ct], acc[rt][ct], 0, 0, 0);

    __syncthreads();
  }

  // epilogue 1: relu(acc + b1) -> Hl bf16. D layout: col=lane&15, row=quad*4+reg
  #pragma unroll
  for (int ct = 0; ct < 4; ++ct) {
    int col = wave*64 + ct*16 + lr;
    float bias = b1v[col];
    #pragma unroll
    for (int rt = 0; rt < 4; ++rt) {
      #pragma unroll
      for (int r = 0; r < 4; ++r) {
        int row = rt*16 + quad*4 + r;
        float v = fmaxf(acc[rt][ct][r] + bias, 0.f);
        Hl[row][col] = f2bf(v);
      }
    }
  }
  __syncthreads();

  // GEMM2: each wave rows wave*16..+15, 48 padded cols, K=256
  f32x4 acc2[3] = {};
  #pragma unroll
  for (int kc2 = 0; kc2 < 8; ++kc2) {
    short8 a2 = *(const short8*)&Hl[wave*16 + lr][kc2*32 + quad*8];
    #pragma unroll
    for (int nt = 0; nt < 3; ++nt) {
      short8 bq = *(const short8*)&W2l[nt*16 + lr][kc2*32 + quad*8];
      acc2[nt] = __builtin_amdgcn_mfma_f32_16x16x32_bf16(a2, bq, acc2[nt], 0, 0, 0);
    }
  }

  // epilogue 2: h2b = bf16(acc2 + b2)
  #pragma unroll
  for (int nt = 0; nt < 3; ++nt) {
    int col = nt*16 + lr;
    if (col < C_OUT) {
      float bias = b2v[col];
      #pragma unroll
      for (int r = 0; r < 4; ++r) {
        int row = row0 + wave*16 + quad*4 + r;
        if (row < N_NODES)
          h2b[(long)row * C_OUT + col] = f2bf(acc2[nt][r] + bias);
      }
    }
  }
}

// ---- K2: per-chunk LDS histogram of buckets (row>>7). offs[b*NCH + c] = count
__global__ __launch_bounds__(256) void k_hist2(
    const int* __restrict__ erow, int* __restrict__ offs, int E, int CH)
{
  __shared__ int h[NBUCK];
  int tid = threadIdx.x, c = blockIdx.x;
  for (int b = tid; b < NBUCK; b += 256) h[b] = 0;
  __syncthreads();
  int e0 = c * CH, e1 = min(E, e0 + CH);
  for (int e = e0 + tid; e < e1; e += 256)
    atomicAdd(&h[erow[e] >> 7], 1);
  __syncthreads();
  for (int b = tid; b < NBUCK; b += 256) offs[b * NCH + c] = h[b];
}

// ---- K3a: scan phase 1 — 2048-elem chunks, in-place exclusive scan + sums
__global__ __launch_bounds__(256) void k_scan1(
    int* __restrict__ offs, int* __restrict__ bsums)
{
  __shared__ int sh[256];
  int tid = threadIdx.x;
  int base = blockIdx.x * SCAN_CHUNK + tid * 8;
  int d[8];
  #pragma unroll
  for (int k = 0; k < 8; ++k)
    d[k] = (base + k < SCAN_M) ? offs[base + k] : 0;
  int s = 0;
  #pragma unroll
  for (int k = 0; k < 8; ++k) s += d[k];
  sh[tid] = s;
  __syncthreads();
  for (int o = 1; o < 256; o <<= 1) {
    int v = (tid >= o) ? sh[tid - o] : 0;
    __syncthreads();
    if (tid >= o) sh[tid] += v;
    __syncthreads();
  }
  int run = sh[tid] - s;
  #pragma unroll
  for (int k = 0; k < 8; ++k) {
    if (base + k < SCAN_M) offs[base + k] = run;
    run += d[k];
  }
  if (tid == 255) bsums[blockIdx.x] = sh[255];
}

// ---- K3b: scan phase 2 — exclusive scan of NBS block sums (single block)
__global__ __launch_bounds__(256) void k_scan2(int* __restrict__ bsums) {
  __shared__ int sh[256];
  int tid = threadIdx.x;
  int v = (tid < NBS) ? bsums[tid] : 0;
  sh[tid] = v;
  __syncthreads();
  for (int o = 1; o < 256; o <<= 1) {
    int u = (tid >= o) ? sh[tid - o] : 0;
    __syncthreads();
    if (tid >= o) sh[tid] += u;
    __syncthreads();
  }
  if (tid < NBS) bsums[tid] = sh[tid] - v;
}

// ---- K3c: scan phase 3 — add block offsets
__global__ __launch_bounds__(256) void k_scan3(
    int* __restrict__ offs, const int* __restrict__ bsums)
{
  int i = blockIdx.x * 256 + threadIdx.x;
  if (i < SCAN_M) offs[i] += bsums[i >> 11];
}

// ---- K4: split edges into bucket-grouped order (LDS cursors, no dev atomics).
// sorted[pos] = { col | rowlow<<17 , val }
__global__ __launch_bounds__(256) void k_split(
    const int* __restrict__ erow, const int* __restrict__ ecol,
    const float* __restrict__ eval, const int* __restrict__ offs,
    int2* __restrict__ sorted, int E, int CH)
{
  __shared__ int cur[NBUCK];
  int tid = threadIdx.x, c = blockIdx.x;
  for (int b = tid; b < NBUCK; b += 256) cur[b] = offs[b * NCH + c];
  __syncthreads();
  int e0 = c * CH, e1 = min(E, e0 + CH);
  for (int e = e0 + tid; e < e1; e += 256) {
    int r = erow[e];
    int b = r >> 7;
    int pos = atomicAdd(&cur[b], 1);
    int2 cv;
    cv.x = ecol[e] | ((r & 127) << 17);
    cv.y = __float_as_int(eval[e]);
    sorted[pos] = cv;
  }
}

// ---- K5: per-bucket CSR finalize. Two contiguous passes over the bucket's
// edges; scatter stays inside the bucket's ~23KB window (L2-merged).
// Produces sorted2 (row-ordered) + row_offs[N+1].
__global__ __launch_bounds__(256) void k_csr(
    const int* __restrict__ offs, const int2* __restrict__ sorted,
    int2* __restrict__ sorted2, int* __restrict__ row_offs, int E)
{
  __shared__ int hist[RPB];
  __shared__ int scn[RPB];
  int tid = threadIdx.x, b = blockIdx.x;
  int start = offs[b * NCH];
  int end   = (b + 1 < NBUCK) ? offs[(b + 1) * NCH] : E;

  if (tid < RPB) hist[tid] = 0;
  __syncthreads();
  for (int e = start + tid; e < end; e += 256)
    atomicAdd(&hist[((unsigned)sorted[e].x) >> 17], 1);
  __syncthreads();
  if (tid < RPB) scn[tid] = hist[tid];
  __syncthreads();
  for (int o = 1; o < RPB; o <<= 1) {
    int v = (tid >= o && tid < RPB) ? scn[tid - o] : 0;
    __syncthreads();
    if (tid >= o && tid < RPB) scn[tid] += v;
    __syncthreads();
  }
  if (tid < RPB) {
    int excl = scn[tid] - hist[tid];
    int row = b * RPB + tid;
    if (row < N_NODES) row_offs[row] = start + excl;
    hist[tid] = excl;   // reuse as in-bucket cursor
  }
  __syncthreads();
  for (int e = start + tid; e < end; e += 256) {
    int2 cv = sorted[e];
    int rl = ((unsigned)cv.x) >> 17;
    int pos = start + atomicAdd(&hist[rl], 1);
    sorted2[pos] = cv;
  }
  if (b == 0 && tid == 0) row_offs[N_NODES] = E;
}

// ---- K6: wave-per-row gather SpMM + fused log_softmax (4 rows/block).
__global__ __launch_bounds__(256) void k_spmm_lsm(
    const int* __restrict__ row_offs, const int2* __restrict__ sorted2,
    const short* __restrict__ h2b, float* __restrict__ out)
{
  int row  = blockIdx.x * 4 + (threadIdx.x >> 6);
  int lane = threadIdx.x & 63;
  if (row >= N_NODES) return;

  float acc = 0.f;
  if (lane < C_OUT) acc = ALPHA0 * bf2f(h2b[(long)row * C_OUT + lane]);

  int e   = row_offs[row];
  int end = row_offs[row + 1];
  // 4x unrolled gather-accumulate (4 indep loads in flight)
  for (; e + 3 < end; e += 4) {
    int2 cv0 = sorted2[e];
    int2 cv1 = sorted2[e + 1];
    int2 cv2 = sorted2[e + 2];
    int2 cv3 = sorted2[e + 3];
    int c0 = cv0.x & 0x1FFFF, c1 = cv1.x & 0x1FFFF;
    int c2 = cv2.x & 0x1FFFF, c3 = cv3.x & 0x1FFFF;
    if (lane < C_OUT) {
      float g0 = bf2f(h2b[(long)c0 * C_OUT + lane]);
      float g1 = bf2f(h2b[(long)c1 * C_OUT + lane]);
      float g2 = bf2f(h2b[(long)c2 * C_OUT + lane]);
      float g3 = bf2f(h2b[(long)c3 * C_OUT + lane]);
      acc += __int_as_float(cv0.y) * g0;
      acc += __int_as_float(cv1.y) * g1;
      acc += __int_as_float(cv2.y) * g2;
      acc += __int_as_float(cv3.y) * g3;
    }
  }
  for (; e < end; ++e) {
    int2 cv = sorted2[e];
    int c0 = cv.x & 0x1FFFF;
    if (lane < C_OUT)
      acc += __int_as_float(cv.y) * bf2f(h2b[(long)c0 * C_OUT + lane]);
  }

  // fused log_softmax over 40 active lanes
  float m = (lane < C_OUT) ? acc : -INFINITY;
  #pragma unroll
  for (int o = 32; o > 0; o >>= 1) m = fmaxf(m, __shfl_xor(m, o));
  float ev = (lane < C_OUT) ? __expf(acc - m) : 0.f;
  float s = ev;
  #pragma unroll
  for (int o = 32; o > 0; o >>= 1) s += __shfl_xor(s, o);
  if (lane < C_OUT) out[(long)row * C_OUT + lane] = acc - m - __logf(s);
}

extern "C" void kernel_launch(void* const* d_in, const int* in_sizes, int n_in,
                              void* d_out, int out_size, void* d_ws, size_t ws_size,
                              hipStream_t stream) {
  const float* x    = (const float*)d_in[0];
  const float* W1   = (const float*)d_in[1];
  const float* b1   = (const float*)d_in[2];
  const float* W2   = (const float*)d_in[3];
  const float* b2   = (const float*)d_in[4];
  const int*   erow = (const int*)d_in[5];
  const int*   ecol = (const int*)d_in[6];
  const float* eval = (const float*)d_in[7];
  const int E  = in_sizes[5];
  const int CH = (E + NCH - 1) / NCH;

  // ws: h2b 8MB | W1S 512KB | W2T 24KB | offs ~1MB | bsums 1KB |
  //     row_offs 400KB | sorted E*8B | sorted2 E*8B   (~47 MB)
  char* p = (char*)d_ws;
  short* h2b      = (short*)p;  p += (size_t)N_NODES * C_OUT * 2;
  short* W1S      = (short*)p;  p += (size_t)16*256*32 * 2;
  short* W2T      = (short*)p;  p += (size_t)48*256 * 2;
  int*   offs     = (int*)p;    p += (size_t)SCAN_M * 4;
  int*   bsums    = (int*)p;    p += 256 * 4;
  int*   row_offs = (int*)p;    p += (size_t)(N_NODES + 4) * 4;
  int2*  sorted   = (int2*)p;   p += (size_t)E * 8;
  int2*  sorted2  = (int2*)p;
  float* out = (float*)d_out;

  k_pack_weights<<<(16*256*32 + 48*256 + 255)/256, 256, 0, stream>>>(W1, W2, W1S, W2T);
  k_fused_mlp<<<(N_NODES + 63)/64, 256, 0, stream>>>(x, b1, b2, W1S, W2T, h2b);
  k_hist2<<<NCH, 256, 0, stream>>>(erow, offs, E, CH);
  k_scan1<<<NBS, 256, 0, stream>>>(offs, bsums);
  k_scan2<<<1, 256, 0, stream>>>(bsums);
  k_scan3<<<(SCAN_M + 255)/256, 256, 0, stream>>>(offs, bsums);
  k_split<<<NCH, 256, 0, stream>>>(erow, ecol, eval, offs, sorted, E, CH);
  k_csr<<<NBUCK, 256, 0, stream>>>(offs, sorted, sorted2, row_offs, E);
  k_spmm_lsm<<<(N_NODES + 3)/4, 256, 0, stream>>>(row_offs, sorted2, h2b, out);
}

// Round 6
// 557.688 us; speedup vs baseline: 1.9610x; 1.0212x over previous
//
#include <hip/hip_runtime.h>
#include <hip/hip_bf16.h>

// LSAPPNP: h = relu(x@W1+b1); h2 = h@W2+b2; agg[r] += val*h2[c] over edges;
// out = log_softmax(0.1*h2 + agg, axis=1)
// N=100000, F_IN=500, HID=256, C=40, E~2.3M
//
// Round 6: MLP rewrite — 128-row tile, 512 thr (8 waves), double-buffered A
// (1 barrier/iter, pipelined), B-frags direct from L2-hot global, Hl via
// XOR-swizzled 64KB LDS. 2 blocks/CU (16 waves) vs prior 8 waves.

#define N_NODES 100000
#define F_IN    500
#define HID     256
#define C_OUT   40
#define ALPHA0  0.1f

#define RPB     128                           // rows per bucket
#define NBUCK   ((N_NODES + RPB - 1) / RPB)   // 782
#define NCH     320                           // edge chunks (hist/split blocks)
#define SCAN_M  (NBUCK * NCH)                 // 250240
#define SCAN_CHUNK 2048
#define NBS     ((SCAN_M + SCAN_CHUNK - 1) / SCAN_CHUNK)  // 123

typedef short short8 __attribute__((ext_vector_type(8)));
typedef float f32x4  __attribute__((ext_vector_type(4)));

__device__ __forceinline__ short f2bf(float f) {
  union { float f; unsigned u; } x; x.f = f;
  unsigned r = x.u + 0x7fffu + ((x.u >> 16) & 1u);  // RNE
  return (short)(r >> 16);
}
__device__ __forceinline__ float bf2f(short s) {
  union { unsigned u; float f; } x; x.u = ((unsigned)(unsigned short)s) << 16;
  return x.f;
}

// ---- K0: pack W1 -> W1S [16 kchunks][256 n][32 k] bf16; W2 -> W2T [48 n][256 k]
__global__ __launch_bounds__(256) void k_pack_weights(
    const float* __restrict__ W1, const float* __restrict__ W2,
    short* __restrict__ W1S, short* __restrict__ W2T)
{
  int i = blockIdx.x * 256 + threadIdx.x;
  if (i < 16*256*32) {
    int kc  = i >> 13;
    int idx = i & 8191;
    int n   = idx >> 5;
    int kk  = idx & 31;
    int k   = kc*32 + kk;
    float v = (k < F_IN) ? W1[k*HID + n] : 0.f;
    W1S[i] = f2bf(v);
  } else {
    int j = i - 16*256*32;
    if (j < 48*256) {
      int n = j >> 8;
      int k = j & 255;
      float v = (n < C_OUT) ? W2[k*C_OUT + n] : 0.f;
      W2T[j] = f2bf(v);
    }
  }
}

// ---- K1: fused MLP. 512 thr = 8 waves (2 row x 4 col), tile 128x256.
// A: LDS double-buffer (pipelined, 1 barrier/iter). B1/B2: global (L2-hot).
// Hl: 64KB LDS, XOR-swizzled 8-col groups (zero padding, few conflicts).
__global__ __launch_bounds__(512, 4) void k_fused_mlp(
    const float* __restrict__ x, const float* __restrict__ b1v,
    const float* __restrict__ b2v,
    const short* __restrict__ W1S, const short* __restrict__ W2T,
    short* __restrict__ h2b)
{
  __shared__ __align__(16) char smem[65536];
  short (*Ab)[128][40] = (short(*)[128][40])smem;   // 2 x 10240 B, dead after K loop
  short (*Hl)[256]     = (short(*)[256])smem;       // 64 KB, used after K loop

  const int tid  = threadIdx.x;
  const int w    = tid >> 6;
  const int lane = tid & 63;
  const int lr   = lane & 15;
  const int quad = lane >> 4;
  const int wr   = w >> 2;      // 0..1 row-wave
  const int wc   = w & 3;       // 0..3 col-wave
  const int row0 = blockIdx.x * 128;

  // A staging mapping: thread -> (row 0..127, seg 0..3 of 8 f32)
  const int srow = tid >> 2;
  const int sseg = tid & 3;
  const int grow = row0 + srow;
  const bool rok = grow < N_NODES;
  const float* ap = x + (size_t)grow * F_IN;

  f32x4 acc[4][4] = {};

  // preload + store iter 0
  float rnxt[8];
  {
    int kb = sseg * 8;
    if (rok) {
      f32x4 u0 = *(const f32x4*)(ap + kb);
      f32x4 u1 = *(const f32x4*)(ap + kb + 4);
      #pragma unroll
      for (int j = 0; j < 4; ++j) { rnxt[j] = u0[j]; rnxt[4+j] = u1[j]; }
    } else {
      #pragma unroll
      for (int j = 0; j < 8; ++j) rnxt[j] = 0.f;
    }
    short tmp[8];
    #pragma unroll
    for (int j = 0; j < 8; ++j) tmp[j] = f2bf(rnxt[j]);
    *(short8*)&Ab[0][srow][sseg*8] = *(short8*)tmp;
  }

  const short* bbase = W1S + (wc*64 + lr)*32 + quad*8;

  for (int kc = 0; kc < 16; ++kc) {
    // issue next iter's global loads (in flight across barrier+MFMA)
    if (kc < 15) {
      int kb = (kc + 1)*32 + sseg*8;
      if (rok && kb + 8 <= F_IN) {
        f32x4 u0 = *(const f32x4*)(ap + kb);
        f32x4 u1 = *(const f32x4*)(ap + kb + 4);
        #pragma unroll
        for (int j = 0; j < 4; ++j) { rnxt[j] = u0[j]; rnxt[4+j] = u1[j]; }
      } else {
        #pragma unroll
        for (int j = 0; j < 8; ++j)
          rnxt[j] = (rok && kb + j < F_IN) ? ap[kb + j] : 0.f;
      }
    }
    __syncthreads();   // Ab[kc&1] visible

    short8 af[4], bf4[4];
    #pragma unroll
    for (int t = 0; t < 4; ++t)
      af[t] = *(const short8*)&Ab[kc & 1][wr*64 + t*16 + lr][quad*8];
    #pragma unroll
    for (int t = 0; t < 4; ++t)
      bf4[t] = *(const short8*)(bbase + kc*8192 + t*16*32);

    #pragma unroll
    for (int rt = 0; rt < 4; ++rt)
      #pragma unroll
      for (int ct = 0; ct < 4; ++ct)
        acc[rt][ct] = __builtin_amdgcn_mfma_f32_16x16x32_bf16(af[rt], bf4[ct], acc[rt][ct], 0, 0, 0);

    // stage next tile into alternate buffer (read last at iter kc-1)
    if (kc < 15) {
      short tmp[8];
      #pragma unroll
      for (int j = 0; j < 8; ++j) tmp[j] = f2bf(rnxt[j]);
      *(short8*)&Ab[(kc + 1) & 1][srow][sseg*8] = *(short8*)tmp;
    }
  }
  __syncthreads();   // all frag reads done; Ab space can be reused as Hl

  // epilogue 1: relu(acc + b1) -> Hl (bf16, XOR-swizzled col groups)
  // D layout: col=lane&15, row=quad*4+reg
  #pragma unroll
  for (int ct = 0; ct < 4; ++ct) {
    int col = wc*64 + ct*16 + lr;
    int cg = col >> 3, ci = col & 7;
    float bias = b1v[col];
    #pragma unroll
    for (int rt = 0; rt < 4; ++rt) {
      #pragma unroll
      for (int r = 0; r < 4; ++r) {
        int row = wr*64 + rt*16 + quad*4 + r;
        float v = fmaxf(acc[rt][ct][r] + bias, 0.f);
        Hl[row][((cg ^ (row & 31)) << 3) | ci] = f2bf(v);
      }
    }
  }
  __syncthreads();

  // GEMM2: wave w handles rows w*16..+15, 48 padded cols, K=256
  f32x4 acc2[3] = {};
  const int arow = w*16 + lr;
  #pragma unroll
  for (int kc2 = 0; kc2 < 8; ++kc2) {
    int gg = kc2*4 + quad;
    short8 a2 = *(const short8*)&Hl[arow][(gg ^ (arow & 31)) << 3];
    #pragma unroll
    for (int nt = 0; nt < 3; ++nt) {
      short8 b2 = *(const short8*)(W2T + (nt*16 + lr)*256 + kc2*32 + quad*8);
      acc2[nt] = __builtin_amdgcn_mfma_f32_16x16x32_bf16(a2, b2, acc2[nt], 0, 0, 0);
    }
  }

  // epilogue 2: h2b = bf16(acc2 + b2)
  #pragma unroll
  for (int nt = 0; nt < 3; ++nt) {
    int col = nt*16 + lr;
    if (col < C_OUT) {
      float bias = b2v[col];
      #pragma unroll
      for (int r = 0; r < 4; ++r) {
        int row = row0 + w*16 + quad*4 + r;
        if (row < N_NODES)
          h2b[(long)row * C_OUT + col] = f2bf(acc2[nt][r] + bias);
      }
    }
  }
}

// ---- K2: per-chunk LDS histogram of buckets (row>>7). offs[b*NCH + c] = count
__global__ __launch_bounds__(256) void k_hist2(
    const int* __restrict__ erow, int* __restrict__ offs, int E, int CH)
{
  __shared__ int h[NBUCK];
  int tid = threadIdx.x, c = blockIdx.x;
  for (int b = tid; b < NBUCK; b += 256) h[b] = 0;
  __syncthreads();
  int e0 = c * CH, e1 = min(E, e0 + CH);
  for (int e = e0 + tid; e < e1; e += 256)
    atomicAdd(&h[erow[e] >> 7], 1);
  __syncthreads();
  for (int b = tid; b < NBUCK; b += 256) offs[b * NCH + c] = h[b];
}

// ---- K3a: scan phase 1 — 2048-elem chunks, in-place exclusive scan + sums
__global__ __launch_bounds__(256) void k_scan1(
    int* __restrict__ offs, int* __restrict__ bsums)
{
  __shared__ int sh[256];
  int tid = threadIdx.x;
  int base = blockIdx.x * SCAN_CHUNK + tid * 8;
  int d[8];
  #pragma unroll
  for (int k = 0; k < 8; ++k)
    d[k] = (base + k < SCAN_M) ? offs[base + k] : 0;
  int s = 0;
  #pragma unroll
  for (int k = 0; k < 8; ++k) s += d[k];
  sh[tid] = s;
  __syncthreads();
  for (int o = 1; o < 256; o <<= 1) {
    int v = (tid >= o) ? sh[tid - o] : 0;
    __syncthreads();
    if (tid >= o) sh[tid] += v;
    __syncthreads();
  }
  int run = sh[tid] - s;
  #pragma unroll
  for (int k = 0; k < 8; ++k) {
    if (base + k < SCAN_M) offs[base + k] = run;
    run += d[k];
  }
  if (tid == 255) bsums[blockIdx.x] = sh[255];
}

// ---- K3b: scan phase 2 — exclusive scan of NBS block sums (single block)
__global__ __launch_bounds__(256) void k_scan2(int* __restrict__ bsums) {
  __shared__ int sh[256];
  int tid = threadIdx.x;
  int v = (tid < NBS) ? bsums[tid] : 0;
  sh[tid] = v;
  __syncthreads();
  for (int o = 1; o < 256; o <<= 1) {
    int u = (tid >= o) ? sh[tid - o] : 0;
    __syncthreads();
    if (tid >= o) sh[tid] += u;
    __syncthreads();
  }
  if (tid < NBS) bsums[tid] = sh[tid] - v;
}

// ---- K3c: scan phase 3 — add block offsets
__global__ __launch_bounds__(256) void k_scan3(
    int* __restrict__ offs, const int* __restrict__ bsums)
{
  int i = blockIdx.x * 256 + threadIdx.x;
  if (i < SCAN_M) offs[i] += bsums[i >> 11];
}

// ---- K4: split edges into bucket-grouped order (LDS cursors, no dev atomics).
// sorted[pos] = { col | rowlow<<17 , val }
__global__ __launch_bounds__(256) void k_split(
    const int* __restrict__ erow, const int* __restrict__ ecol,
    const float* __restrict__ eval, const int* __restrict__ offs,
    int2* __restrict__ sorted, int E, int CH)
{
  __shared__ int cur[NBUCK];
  int tid = threadIdx.x, c = blockIdx.x;
  for (int b = tid; b < NBUCK; b += 256) cur[b] = offs[b * NCH + c];
  __syncthreads();
  int e0 = c * CH, e1 = min(E, e0 + CH);
  for (int e = e0 + tid; e < e1; e += 256) {
    int r = erow[e];
    int b = r >> 7;
    int pos = atomicAdd(&cur[b], 1);
    int2 cv;
    cv.x = ecol[e] | ((r & 127) << 17);
    cv.y = __float_as_int(eval[e]);
    sorted[pos] = cv;
  }
}

// ---- K5: per-bucket CSR finalize -> sorted2 (row-ordered) + row_offs[N+1]
__global__ __launch_bounds__(256) void k_csr(
    const int* __restrict__ offs, const int2* __restrict__ sorted,
    int2* __restrict__ sorted2, int* __restrict__ row_offs, int E)
{
  __shared__ int hist[RPB];
  __shared__ int scn[RPB];
  int tid = threadIdx.x, b = blockIdx.x;
  int start = offs[b * NCH];
  int end   = (b + 1 < NBUCK) ? offs[(b + 1) * NCH] : E;

  if (tid < RPB) hist[tid] = 0;
  __syncthreads();
  for (int e = start + tid; e < end; e += 256)
    atomicAdd(&hist[((unsigned)sorted[e].x) >> 17], 1);
  __syncthreads();
  if (tid < RPB) scn[tid] = hist[tid];
  __syncthreads();
  for (int o = 1; o < RPB; o <<= 1) {
    int v = (tid >= o && tid < RPB) ? scn[tid - o] : 0;
    __syncthreads();
    if (tid >= o && tid < RPB) scn[tid] += v;
    __syncthreads();
  }
  if (tid < RPB) {
    int excl = scn[tid] - hist[tid];
    int row = b * RPB + tid;
    if (row < N_NODES) row_offs[row] = start + excl;
    hist[tid] = excl;   // reuse as in-bucket cursor
  }
  __syncthreads();
  for (int e = start + tid; e < end; e += 256) {
    int2 cv = sorted[e];
    int rl = ((unsigned)cv.x) >> 17;
    int pos = start + atomicAdd(&hist[rl], 1);
    sorted2[pos] = cv;
  }
  if (b == 0 && tid == 0) row_offs[N_NODES] = E;
}

// ---- K6: wave-per-row gather SpMM + fused log_softmax (4 rows/block).
__global__ __launch_bounds__(256) void k_spmm_lsm(
    const int* __restrict__ row_offs, const int2* __restrict__ sorted2,
    const short* __restrict__ h2b, float* __restrict__ out)
{
  int row  = blockIdx.x * 4 + (threadIdx.x >> 6);
  int lane = threadIdx.x & 63;
  if (row >= N_NODES) return;

  float acc = 0.f;
  if (lane < C_OUT) acc = ALPHA0 * bf2f(h2b[(long)row * C_OUT + lane]);

  int e   = row_offs[row];
  int end = row_offs[row + 1];
  for (; e + 3 < end; e += 4) {
    int2 cv0 = sorted2[e];
    int2 cv1 = sorted2[e + 1];
    int2 cv2 = sorted2[e + 2];
    int2 cv3 = sorted2[e + 3];
    int c0 = cv0.x & 0x1FFFF, c1 = cv1.x & 0x1FFFF;
    int c2 = cv2.x & 0x1FFFF, c3 = cv3.x & 0x1FFFF;
    if (lane < C_OUT) {
      float g0 = bf2f(h2b[(long)c0 * C_OUT + lane]);
      float g1 = bf2f(h2b[(long)c1 * C_OUT + lane]);
      float g2 = bf2f(h2b[(long)c2 * C_OUT + lane]);
      float g3 = bf2f(h2b[(long)c3 * C_OUT + lane]);
      acc += __int_as_float(cv0.y) * g0;
      acc += __int_as_float(cv1.y) * g1;
      acc += __int_as_float(cv2.y) * g2;
      acc += __int_as_float(cv3.y) * g3;
    }
  }
  for (; e < end; ++e) {
    int2 cv = sorted2[e];
    int c0 = cv.x & 0x1FFFF;
    if (lane < C_OUT)
      acc += __int_as_float(cv.y) * bf2f(h2b[(long)c0 * C_OUT + lane]);
  }

  float m = (lane < C_OUT) ? acc : -INFINITY;
  #pragma unroll
  for (int o = 32; o > 0; o >>= 1) m = fmaxf(m, __shfl_xor(m, o));
  float ev = (lane < C_OUT) ? __expf(acc - m) : 0.f;
  float s = ev;
  #pragma unroll
  for (int o = 32; o > 0; o >>= 1) s += __shfl_xor(s, o);
  if (lane < C_OUT) out[(long)row * C_OUT + lane] = acc - m - __logf(s);
}

extern "C" void kernel_launch(void* const* d_in, const int* in_sizes, int n_in,
                              void* d_out, int out_size, void* d_ws, size_t ws_size,
                              hipStream_t stream) {
  const float* x    = (const float*)d_in[0];
  const float* W1   = (const float*)d_in[1];
  const float* b1   = (const float*)d_in[2];
  const float* W2   = (const float*)d_in[3];
  const float* b2   = (const float*)d_in[4];
  const int*   erow = (const int*)d_in[5];
  const int*   ecol = (const int*)d_in[6];
  const float* eval = (const float*)d_in[7];
  const int E  = in_sizes[5];
  const int CH = (E + NCH - 1) / NCH;

  // ws: h2b 8MB | W1S 256KB | W2T 24KB | offs ~1MB | bsums 1KB |
  //     row_offs 400KB | sorted E*8B | sorted2 E*8B   (~47 MB)
  char* p = (char*)d_ws;
  short* h2b      = (short*)p;  p += (size_t)N_NODES * C_OUT * 2;
  short* W1S      = (short*)p;  p += (size_t)16*256*32 * 2;
  short* W2T      = (short*)p;  p += (size_t)48*256 * 2;
  int*   offs     = (int*)p;    p += (size_t)SCAN_M * 4;
  int*   bsums    = (int*)p;    p += 256 * 4;
  int*   row_offs = (int*)p;    p += (size_t)(N_NODES + 4) * 4;
  int2*  sorted   = (int2*)p;   p += (size_t)E * 8;
  int2*  sorted2  = (int2*)p;
  float* out = (float*)d_out;

  k_pack_weights<<<(16*256*32 + 48*256 + 255)/256, 256, 0, stream>>>(W1, W2, W1S, W2T);
  k_fused_mlp<<<(N_NODES + 127)/128, 512, 0, stream>>>(x, b1, b2, W1S, W2T, h2b);
  k_hist2<<<NCH, 256, 0, stream>>>(erow, offs, E, CH);
  k_scan1<<<NBS, 256, 0, stream>>>(offs, bsums);
  k_scan2<<<1, 256, 0, stream>>>(bsums);
  k_scan3<<<(SCAN_M + 255)/256, 256, 0, stream>>>(offs, bsums);
  k_split<<<NCH, 256, 0, stream>>>(erow, ecol, eval, offs, sorted, E, CH);
  k_csr<<<NBUCK, 256, 0, stream>>>(offs, sorted, sorted2, row_offs, E);
  k_spmm_lsm<<<(N_NODES + 3)/4, 256, 0, stream>>>(row_offs, sorted2, h2b, out);
}